// Round 2
// baseline (519.474 us; speedup 1.0000x reference)
//
#include <hip/hip_runtime.h>
#include <math.h>

#define B_ 32
#define S_ 4096
#define CTXD_ 512
#define QD_ 512
#define ATTD_ 256

#define KT 64      // k-chunk (two MFMA K-slices)
#define RT 64      // rows (s) per block

#define MASKED_SCORE (-1e30f)

typedef __attribute__((ext_vector_type(8))) short bf16x8;   // 8 bf16 = 4 VGPR
typedef __attribute__((ext_vector_type(4))) float f32x4;    // MFMA C/D

// fp32 -> bf16 round-to-nearest-even (inputs are finite randoms)
__device__ __forceinline__ unsigned short f2bf(float f) {
    unsigned u = __float_as_uint(f);
    u += 0x7fff + ((u >> 16) & 1);
    return (unsigned short)(u >> 16);
}
__device__ __forceinline__ unsigned pk2(float lo, float hi) {
    return (unsigned)f2bf(lo) | ((unsigned)f2bf(hi) << 16);
}

__device__ __forceinline__ float fast_tanh(float x) {
    float xc = fminf(fmaxf(x, -15.f), 15.f);
    float t = __expf(2.f * xc);
    return (t - 1.f) / (t + 1.f);
}

// ---------------------------------------------------------------------------
// Kernel 0: Wt[n][k] = bf16(W[k][n]) — transpose+convert ctx half of W.
// ---------------------------------------------------------------------------
__global__ __launch_bounds__(256) void wt_kernel(const float* __restrict__ W,
                                                 unsigned short* __restrict__ Wt) {
    const int n = blockIdx.x;   // 0..255
    const int t = threadIdx.x;  // 0..255
    Wt[n * CTXD_ + t] = f2bf(W[(size_t)t * ATTD_ + n]);
    Wt[n * CTXD_ + t + 256] = f2bf(W[(size_t)(t + 256) * ATTD_ + n]);
}

// ---------------------------------------------------------------------------
// Kernel 1: qh[b][a] = bias[a] + qry[b] @ W_qry  (fp32, tiny)
// ---------------------------------------------------------------------------
__global__ __launch_bounds__(256) void qh_kernel(const float* __restrict__ qry,
                                                 const float* __restrict__ W,
                                                 const float* __restrict__ bias,
                                                 float* __restrict__ qh) {
    __shared__ float q[QD_];
    const int b = blockIdx.x, t = threadIdx.x;
    for (int i = t; i < QD_; i += 256) q[i] = qry[b * QD_ + i];
    __syncthreads();
    float acc = bias[t];
    const float* Wq = W + (size_t)CTXD_ * ATTD_ + t;
    #pragma unroll 8
    for (int k = 0; k < QD_; ++k) acc += q[k] * Wq[(size_t)k * ATTD_];
    qh[b * ATTD_ + t] = acc;
}

// ---------------------------------------------------------------------------
// Kernel 2: MFMA scores. KT=64: 8 chunks, 2 barriers each. Waves tiled 2Mx2N
// (32 rows x 128 cols per wave): per chunk each wave does 4 A-frag + 16
// B-frag ds_reads feeding 32 MFMAs (B frags reused across 2 M-tiles).
// Register prefetch of chunk k+1 (A from HBM, B from L2) issued right after
// the store barrier, drained by the next store barrier.
// ---------------------------------------------------------------------------
__global__ __launch_bounds__(256, 3) void scores_kernel(
    const float* __restrict__ ctx, const unsigned short* __restrict__ Wt,
    const float* __restrict__ qh, const float* __restrict__ w2,
    const float* __restrict__ b2, const int* __restrict__ mask,
    float* __restrict__ scores) {
    __shared__ unsigned char lds_a[RT * 144];     // 64 rows x (64 bf16 + 16B pad) = 9216 B
    __shared__ unsigned char lds_b[ATTD_ * 144];  // 256 rows                      = 36864 B
    const int t = threadIdx.x;
    const int b = blockIdx.y;
    const int s0 = blockIdx.x * RT;
    const int tx = t & 63;  // lane
    const int w = t >> 6;   // wave
    const int wm = w & 1;   // M half: rows wm*32..+32
    const int wn = w >> 1;  // N half: cols wn*128..+128
    const int frow = tx & 15;
    const int fq = tx >> 4;  // 0..3

    f32x4 c00, c01, c02, c03, c04, c05, c06, c07;
    f32x4 c10, c11, c12, c13, c14, c15, c16, c17;
    c00 = c01 = c02 = c03 = c04 = c05 = c06 = c07 = (f32x4)0.f;
    c10 = c11 = c12 = c13 = c14 = c15 = c16 = c17 = (f32x4)0.f;

    const float* ctxb = ctx + ((size_t)b * S_ + s0) * CTXD_;
    const int arow = t >> 2;  // staging row 0..63
    const int akq = t & 3;    // 16-float quarter of the 64-k chunk
    const int bn = t;         // B staging row 0..255

    const unsigned char* aBase = lds_a + (wm * 32 + frow) * 144 + fq * 16;
    const unsigned char* bBase = lds_b + (wn * 128 + frow) * 144 + fq * 16;

    // prefetch chunk 0
    const float* sA = ctxb + (size_t)arow * CTXD_ + akq * 16;
    float4 fa0 = ((const float4*)sA)[0];
    float4 fa1 = ((const float4*)sA)[1];
    float4 fa2 = ((const float4*)sA)[2];
    float4 fa3 = ((const float4*)sA)[3];
    const uint4* sB = (const uint4*)(Wt + (size_t)bn * CTXD_);
    uint4 pb0 = sB[0], pb1 = sB[1], pb2 = sB[2], pb3 = sB[3];
    uint4 pb4 = sB[4], pb5 = sB[5], pb6 = sB[6], pb7 = sB[7];

#define MM1(ni, ks, C0, C1)                                                  \
    {                                                                        \
        bf16x8 bf = *(const bf16x8*)(bBase + (ni) * (16 * 144) + (ks) * 64); \
        C0 = __builtin_amdgcn_mfma_f32_16x16x32_bf16(a0, bf, C0, 0, 0, 0);   \
        C1 = __builtin_amdgcn_mfma_f32_16x16x32_bf16(a1, bf, C1, 0, 0, 0);   \
    }
#define MMK(ks)                                                              \
    {                                                                        \
        bf16x8 a0 = *(const bf16x8*)(aBase + (ks) * 64);                     \
        bf16x8 a1 = *(const bf16x8*)(aBase + 16 * 144 + (ks) * 64);          \
        MM1(0, ks, c00, c10) MM1(1, ks, c01, c11) MM1(2, ks, c02, c12)       \
        MM1(3, ks, c03, c13) MM1(4, ks, c04, c14) MM1(5, ks, c05, c15)       \
        MM1(6, ks, c06, c16) MM1(7, ks, c07, c17)                            \
    }

    #pragma unroll 1
    for (int k0 = 0; k0 < CTXD_; k0 += KT) {
        __syncthreads();  // prior frag reads done; also drains prefetch vmcnt
        {
            uint4 p;
            p.x = pk2(fa0.x, fa0.y); p.y = pk2(fa0.z, fa0.w);
            p.z = pk2(fa1.x, fa1.y); p.w = pk2(fa1.z, fa1.w);
            *(uint4*)(lds_a + arow * 144 + akq * 32) = p;
            p.x = pk2(fa2.x, fa2.y); p.y = pk2(fa2.z, fa2.w);
            p.z = pk2(fa3.x, fa3.y); p.w = pk2(fa3.z, fa3.w);
            *(uint4*)(lds_a + arow * 144 + akq * 32 + 16) = p;
            uint4* bw = (uint4*)(lds_b + bn * 144);
            bw[0] = pb0; bw[1] = pb1; bw[2] = pb2; bw[3] = pb3;
            bw[4] = pb4; bw[5] = pb5; bw[6] = pb6; bw[7] = pb7;
        }
        __syncthreads();
        // issue next chunk's global loads NOW — overlap with MFMA below
        if (k0 + KT < CTXD_) {
            const float* sA2 = ctxb + (size_t)arow * CTXD_ + (k0 + KT) + akq * 16;
            fa0 = ((const float4*)sA2)[0];
            fa1 = ((const float4*)sA2)[1];
            fa2 = ((const float4*)sA2)[2];
            fa3 = ((const float4*)sA2)[3];
            const uint4* sB2 = (const uint4*)(Wt + (size_t)bn * CTXD_ + (k0 + KT));
            pb0 = sB2[0]; pb1 = sB2[1]; pb2 = sB2[2]; pb3 = sB2[3];
            pb4 = sB2[4]; pb5 = sB2[5]; pb6 = sB2[6]; pb7 = sB2[7];
        }
        MMK(0)
        MMK(1)
    }
#undef MMK
#undef MM1

    // Epilogue: lane holds D[row = wm*32 + mi*16 + fq*4 + r][col = wn*128 + ni*16 + frow]
    const float* qhb = qh + b * ATTD_ + wn * 128;
    const float* w2b = w2 + wn * 128;
    float p00 = 0.f, p01 = 0.f, p02 = 0.f, p03 = 0.f;
    float p10 = 0.f, p11 = 0.f, p12 = 0.f, p13 = 0.f;
#define EPI(ni, C0, C1)                                                      \
    {                                                                        \
        float qv = qhb[(ni) * 16 + frow];                                    \
        float wv = w2b[(ni) * 16 + frow];                                    \
        p00 += fast_tanh(C0[0] + qv) * wv;                                   \
        p01 += fast_tanh(C0[1] + qv) * wv;                                   \
        p02 += fast_tanh(C0[2] + qv) * wv;                                   \
        p03 += fast_tanh(C0[3] + qv) * wv;                                   \
        p10 += fast_tanh(C1[0] + qv) * wv;                                   \
        p11 += fast_tanh(C1[1] + qv) * wv;                                   \
        p12 += fast_tanh(C1[2] + qv) * wv;                                   \
        p13 += fast_tanh(C1[3] + qv) * wv;                                   \
    }
    EPI(0, c00, c10) EPI(1, c01, c11) EPI(2, c02, c12) EPI(3, c03, c13)
    EPI(4, c04, c14) EPI(5, c05, c15) EPI(6, c06, c16) EPI(7, c07, c17)
#undef EPI
    // reduce across the 16 frow lanes (xor bits 0..3 stay within 16-groups)
    #pragma unroll
    for (int off = 1; off <= 8; off <<= 1) {
        p00 += __shfl_xor(p00, off, 64);
        p01 += __shfl_xor(p01, off, 64);
        p02 += __shfl_xor(p02, off, 64);
        p03 += __shfl_xor(p03, off, 64);
        p10 += __shfl_xor(p10, off, 64);
        p11 += __shfl_xor(p11, off, 64);
        p12 += __shfl_xor(p12, off, 64);
        p13 += __shfl_xor(p13, off, 64);
    }
    // combine the two N-half waves via LDS (reuse lds_a)
    float* sred = (float*)lds_a;  // 128 floats: [wn][row]
    __syncthreads();              // all MFMA-phase LDS reads done
    if (frow == 0) {
        const int base = wn * 64 + wm * 32 + fq * 4;
        sred[base + 0] = p00; sred[base + 1] = p01;
        sred[base + 2] = p02; sred[base + 3] = p03;
        sred[base + 16 + 0] = p10; sred[base + 16 + 1] = p11;
        sred[base + 16 + 2] = p12; sred[base + 16 + 3] = p13;
    }
    __syncthreads();
    if (t < 64) {
        const int s = s0 + t;
        float sc = sred[t] + sred[64 + t] + b2[0];
        if (mask[b * S_ + s] == 0) sc = MASKED_SCORE;
        scores[b * S_ + s] = sc;
    }
}

// ---------------------------------------------------------------------------
// Kernel 3: softmax over S per batch row.
// ---------------------------------------------------------------------------
__global__ __launch_bounds__(256) void softmax_kernel(
    const float* __restrict__ scores, float* __restrict__ alphas) {
    const int b = blockIdx.x, t = threadIdx.x;
    __shared__ float red[256];
    float v[16];
    float m = -INFINITY;
    #pragma unroll
    for (int i = 0; i < 16; ++i) {
        v[i] = scores[b * S_ + t + i * 256];
        m = fmaxf(m, v[i]);
    }
    red[t] = m;
    __syncthreads();
    for (int o = 128; o >= 1; o >>= 1) {
        if (t < o) red[t] = fmaxf(red[t], red[t + o]);
        __syncthreads();
    }
    m = red[0];
    __syncthreads();
    float sum = 0.f;
    #pragma unroll
    for (int i = 0; i < 16; ++i) {
        v[i] = expf(v[i] - m);
        sum += v[i];
    }
    red[t] = sum;
    __syncthreads();
    for (int o = 128; o >= 1; o >>= 1) {
        if (t < o) red[t] += red[t + o];
        __syncthreads();
    }
    float inv = 1.0f / red[0];
    #pragma unroll
    for (int i = 0; i < 16; ++i)
        alphas[b * S_ + t + i * 256] = v[i] * inv;
}

// ---------------------------------------------------------------------------
// Kernel 4: partial summaries (split-S). 8-deep load ILP: each thread owns
// two float4 columns (c, c+256), four s-rows in flight (t>>6), unroll 4.
// ---------------------------------------------------------------------------
__global__ __launch_bounds__(256) void summary_part_kernel(
    const float* __restrict__ ctx, const float* __restrict__ alphas,
    float* __restrict__ part, int nch, int cs) {
    const int b = blockIdx.y, ch = blockIdx.x, t = threadIdx.x;
    const int col = t & 63;  // float4 index 0..63 (cols 4c and 4c+256)
    const int q = t >> 6;    // 0..3: s ≡ q (mod 4)
    const int s0 = ch * cs;
    float4 alo = make_float4(0.f, 0.f, 0.f, 0.f);
    float4 ahi = make_float4(0.f, 0.f, 0.f, 0.f);
    const float* cp = ctx + ((size_t)b * S_ + s0) * CTXD_;
    const float* ap = alphas + b * S_ + s0;
    #pragma unroll 4
    for (int s = q; s < cs; s += 4) {
        float al = ap[s];
        const float4* row = (const float4*)(cp + (size_t)s * CTXD_);
        float4 v0 = row[col];
        float4 v1 = row[col + 64];
        alo.x += v0.x * al; alo.y += v0.y * al;
        alo.z += v0.z * al; alo.w += v0.w * al;
        ahi.x += v1.x * al; ahi.y += v1.y * al;
        ahi.z += v1.z * al; ahi.w += v1.w * al;
    }
    __shared__ float4 buf[4][128];
    buf[q][col] = alo;
    buf[q][col + 64] = ahi;
    __syncthreads();
    if (t < 128) {
        float4 a0 = buf[0][t], a1 = buf[1][t], a2 = buf[2][t], a3 = buf[3][t];
        float4 r;
        r.x = a0.x + a1.x + a2.x + a3.x;
        r.y = a0.y + a1.y + a2.y + a3.y;
        r.z = a0.z + a1.z + a2.z + a3.z;
        r.w = a0.w + a1.w + a2.w + a3.w;
        ((float4*)(part + ((size_t)(b * nch + ch)) * CTXD_))[t] = r;
    }
}

// ---------------------------------------------------------------------------
// Kernel 5: reduce partials -> summary
// ---------------------------------------------------------------------------
__global__ __launch_bounds__(256) void summary_reduce_kernel(
    const float* __restrict__ part, float* __restrict__ summary, int nch) {
    const int b = blockIdx.x, t = threadIdx.x;
    for (int c = t; c < CTXD_; c += 256) {
        float s = 0.f;
        for (int ch = 0; ch < nch; ++ch)
            s += part[((size_t)(b * nch + ch)) * CTXD_ + c];
        summary[b * CTXD_ + c] = s;
    }
}

extern "C" void kernel_launch(void* const* d_in, const int* in_sizes, int n_in,
                              void* d_out, int out_size, void* d_ws,
                              size_t ws_size, hipStream_t stream) {
    const float* qry = (const float*)d_in[0];
    const float* ctx = (const float*)d_in[1];
    const int* mask = (const int*)d_in[2];
    const float* W = (const float*)d_in[3];
    const float* bias = (const float*)d_in[4];
    const float* w2 = (const float*)d_in[5];
    const float* b2 = (const float*)d_in[6];

    float* out = (float*)d_out;
    float* alphas = out;                         // B*S
    float* summary = out + B_ * S_;              // B*CTXD
    float* scores = out + B_ * S_ + B_ * CTXD_;  // B*S

    // ws layout: [Wt bf16 256KB][qh 32KB][part ...]
    unsigned short* Wt = (unsigned short*)d_ws;
    float* qh = (float*)((char*)d_ws + (size_t)ATTD_ * CTXD_ * 2);
    float* part = qh + B_ * ATTD_;
    const size_t fixed_bytes = (size_t)ATTD_ * CTXD_ * 2 + (size_t)B_ * ATTD_ * 4;

    int nch = 64;
    while (nch > 1 && fixed_bytes + (size_t)B_ * nch * CTXD_ * 4 > ws_size)
        nch >>= 1;
    const int cs = S_ / nch;

    wt_kernel<<<ATTD_, 256, 0, stream>>>(W, Wt);
    qh_kernel<<<B_, 256, 0, stream>>>(qry, W, bias, qh);
    scores_kernel<<<dim3(S_ / RT, B_), 256, 0, stream>>>(ctx, Wt, qh, w2, b2,
                                                         mask, scores);
    softmax_kernel<<<B_, 256, 0, stream>>>(scores, alphas);
    summary_part_kernel<<<dim3(nch, B_), 256, 0, stream>>>(ctx, alphas, part,
                                                           nch, cs);
    summary_reduce_kernel<<<B_, 256, 0, stream>>>(part, summary, nch);
}